// Round 2
// baseline (103.109 us; speedup 1.0000x reference)
//
#include <hip/hip_runtime.h>
#include <math.h>

// 10-qubit real-amplitude circuit simulator, batch 16384, depth 8.
// Layout: 8 lanes per batch element (index bits [2:0] = lane&7),
//         128 VGPRs per lane (index bits [9:3] = register index).
// Qubit q lives at index bit (9-q):
//   q0..q6 -> register bits 6..0 ; q7,q8,q9 -> lane bits 2,1,0.

// ---- cross-lane helpers -------------------------------------------------
template<int CTRL>
__device__ __forceinline__ float dpp_xor(float x) {
  int i = __builtin_bit_cast(int, x);
  i = __builtin_amdgcn_update_dpp(i, i, CTRL, 0xf, 0xf, true);
  return __builtin_bit_cast(float, i);
}
// lane ^ 1 : quad_perm [1,0,3,2]  (VALU)
__device__ __forceinline__ float xl1(float x) { return dpp_xor<0xB1>(x); }
// lane ^ 2 : quad_perm [2,3,0,1]  (VALU)
__device__ __forceinline__ float xl2(float x) { return dpp_xor<0x4E>(x); }
// lane ^ 4 : ds_swizzle BitMode xor=4, and=0x1F  (DS pipe)
__device__ __forceinline__ float xl4(float x) {
  int i = __builtin_bit_cast(int, x);
  i = __builtin_amdgcn_ds_swizzle(i, 0x101F);
  return __builtin_bit_cast(float, i);
}
// sum across the 8 lanes of a group (lane bits 0..2)
__device__ __forceinline__ float red8(float x) {
  x += xl1(x); x += xl2(x); x += xl4(x); return x;
}

// ---- RY on a register-bit qubit: pairs (r, r|M), s0'=c*s0-s*s1, s1'=s*s0+c*s1
template<int M>
__device__ __forceinline__ void ry_reg(float* v, float c, float s) {
  #pragma unroll
  for (int r = 0; r < 128; ++r) {
    if ((r & M) == 0) {
      float s0 = v[r], s1 = v[r + M];
      v[r]     = fmaf(c, s0, -(s * s1));
      v[r + M] = fmaf(s, s0,  c * s1);
    }
  }
}

// ---- RY on a lane-bit qubit: partner via xor-shuffle, ss = (bit? s : -s)
template<int LM>
__device__ __forceinline__ void ry_lane(float* v, float c, float ss) {
  #pragma unroll
  for (int r = 0; r < 128; ++r) {
    float p = (LM == 4) ? xl4(v[r]) : (LM == 2) ? xl2(v[r]) : xl1(v[r]);
    v[r] = fmaf(c, v[r], ss * p);
  }
}

// ---- one level of the sum/diff tree for expectation values
// Input: v[0..2*L2-1]; writes pairwise sums into v[0..L2-1];
// returns sum of (even - odd) = sum_r w[r] * (-1)^(bit_b(r)) for this level.
template<int L2>
__device__ __forceinline__ float tree_level(float* v) {
  float a = 0.f, b = 0.f;
  #pragma unroll
  for (int j = 0; j < L2; ++j) {
    float e = v[2 * j], o = v[2 * j + 1];
    if (j & 1) b += e - o; else a += e - o;
    v[j] = e + o;
  }
  return a + b;
}

__global__ __launch_bounds__(256) void circuit_kernel(
    const float* __restrict__ x, const float* __restrict__ params,
    float* __restrict__ out) {
  // per-wave staging area: 8 rows x 392 floats (half a row each phase)
  __shared__ float stage[4][8][392];
  __shared__ float csh[160];  // cos/sin of pi*tanh(param)/2, [l*20 + 2q {+1}]

  const int tid  = threadIdx.x;
  const int wv   = tid >> 6;    // wave within block (0..3)
  const int lane = tid & 63;
  const int g    = lane >> 3;   // element group within wave (0..7)
  const int l3   = lane & 7;    // lane within group = index bits [2:0]
  const long elemBase = (long)blockIdx.x * 32 + (long)wv * 8;
  const long elem     = elemBase + g;

  // ---- angles: 80 x (tanh, cos, sin) once per block ----------------------
  if (tid < 80) {
    float th = 1.57079632679489662f * tanhf(params[tid]);  // (pi*tanh)/2
    csh[2 * tid]     = cosf(th);
    csh[2 * tid + 1] = sinf(th);
  }

  float v[128];

  // ---- load 784 cols via coalesced float4 -> LDS -> registers ------------
  #pragma unroll
  for (int h = 0; h < 2; ++h) {
    #pragma unroll
    for (int t = 0; t < 13; ++t) {
      int f = t * 64 + lane;            // float4 index within 8x392 chunk
      if (f < 784) {
        int row = f / 98;               // which of the 8 rows
        int c4  = f - row * 98;         // float4 col within the 392-chunk
        float4 val = reinterpret_cast<const float4*>(
            x + (elemBase + row) * 784 + h * 392)[c4];
        reinterpret_cast<float4*>(&stage[wv][row][0])[c4] = val;
      }
    }
    __syncthreads();
    #pragma unroll
    for (int k = 0; k < 49; ++k)
      v[h * 49 + k] = stage[wv][g][k * 8 + l3];
    __syncthreads();
  }
  #pragma unroll
  for (int r = 98; r < 128; ++r) v[r] = 0.f;   // pad 784 -> 1024

  // ---- L2 normalize ------------------------------------------------------
  float nn = 0.f;
  #pragma unroll
  for (int r = 0; r < 98; ++r) nn = fmaf(v[r], v[r], nn);
  nn = red8(nn);
  float scl = 1.0f / sqrtf(nn);
  #pragma unroll
  for (int r = 0; r < 98; ++r) v[r] *= scl;

  // ---- 8 layers ----------------------------------------------------------
  #pragma unroll 1
  for (int l = 0; l < 8; ++l) {
    // CNOT group 0: (0,1),(2,3),(4,5) = register swaps; (6,7),(8,9) cross-lane
    #pragma unroll
    for (int r = 64; r < 96; ++r) { float t = v[r]; v[r] = v[r + 32]; v[r + 32] = t; }
    #pragma unroll
    for (int r = 0; r < 128; ++r) if ((r & 24) == 16) { float t = v[r]; v[r] = v[r + 8]; v[r + 8] = t; }
    #pragma unroll
    for (int r = 0; r < 128; ++r) if ((r & 6) == 4) { float t = v[r]; v[r] = v[r + 2]; v[r + 2] = t; }
    // (6,7): control = reg bit0, target = lane bit2
    #pragma unroll
    for (int r = 1; r < 128; r += 2) v[r] = xl4(v[r]);
    // (8,9): control = lane bit1, target = lane bit0
    {
      bool c = (lane & 2) != 0;
      #pragma unroll
      for (int r = 0; r < 128; ++r) { float t = xl1(v[r]); v[r] = c ? t : v[r]; }
    }
    // CNOT group 1: (1,2),(3,4),(5,6) = register swaps; (7,8) cross-lane
    #pragma unroll
    for (int r = 0; r < 128; ++r) if ((r & 48) == 32) { float t = v[r]; v[r] = v[r + 16]; v[r + 16] = t; }
    #pragma unroll
    for (int r = 0; r < 128; ++r) if ((r & 12) == 8) { float t = v[r]; v[r] = v[r + 4]; v[r + 4] = t; }
    #pragma unroll
    for (int r = 0; r < 128; ++r) if ((r & 3) == 2) { float t = v[r]; v[r] = v[r + 1]; v[r + 1] = t; }
    // (7,8): control = lane bit2, target = lane bit1
    {
      bool c = (lane & 4) != 0;
      #pragma unroll
      for (int r = 0; r < 128; ++r) { float t = xl2(v[r]); v[r] = c ? t : v[r]; }
    }

    // RY gates q0..q9
    const float* cl = &csh[l * 20];
    ry_reg<64>(v, cl[0],  cl[1]);    // q0
    ry_reg<32>(v, cl[2],  cl[3]);    // q1
    ry_reg<16>(v, cl[4],  cl[5]);    // q2
    ry_reg< 8>(v, cl[6],  cl[7]);    // q3
    ry_reg< 4>(v, cl[8],  cl[9]);    // q4
    ry_reg< 2>(v, cl[10], cl[11]);   // q5
    ry_reg< 1>(v, cl[12], cl[13]);   // q6
    { float s = cl[15]; float ss = (lane & 4) ? s : -s; ry_lane<4>(v, cl[14], ss); } // q7
    { float s = cl[17]; float ss = (lane & 2) ? s : -s; ry_lane<2>(v, cl[16], ss); } // q8
    { float s = cl[19]; float ss = (lane & 1) ? s : -s; ry_lane<1>(v, cl[18], ss); } // q9
  }

  // ---- expectation values ------------------------------------------------
  float z[10];
  #pragma unroll
  for (int r = 0; r < 128; ++r) v[r] *= v[r];   // probabilities
  // register-bit qubits: tree level b -> qubit 6-b
  z[6] = red8(tree_level<64>(v));
  z[5] = red8(tree_level<32>(v));
  z[4] = red8(tree_level<16>(v));
  z[3] = red8(tree_level< 8>(v));
  z[2] = red8(tree_level< 4>(v));
  z[1] = red8(tree_level< 2>(v));
  z[0] = red8(tree_level< 1>(v));
  float W = v[0];  // per-lane total probability
  // lane-bit qubits: signed reductions over the group
  { float u = W + xl1(W); u += xl2(u); float t = u - xl4(u); z[7] = (lane & 4) ? -t : t; }
  { float u = W + xl1(W); float t = u - xl2(u); t += xl4(t); z[8] = (lane & 2) ? -t : t; }
  { float t = W - xl1(W); t += xl2(t); t += xl4(t);          z[9] = (lane & 1) ? -t : t; }

  // ---- store: lane l3 writes column l3 (+ columns 8,9 from lanes 0,1) ----
  float o1 = z[0];
  #pragma unroll
  for (int j = 1; j < 8; ++j) o1 = (l3 == j) ? z[j] : o1;
  out[elem * 10 + l3] = o1;
  if (l3 < 2) out[elem * 10 + 8 + l3] = (l3 == 0) ? z[8] : z[9];
}

extern "C" void kernel_launch(void* const* d_in, const int* in_sizes, int n_in,
                              void* d_out, int out_size, void* d_ws, size_t ws_size,
                              hipStream_t stream) {
  const float* x      = (const float*)d_in[0];   // [16384, 784]
  const float* params = (const float*)d_in[1];   // [8, 10]
  float* out          = (float*)d_out;           // [16384, 10]
  (void)d_ws; (void)ws_size; (void)in_sizes; (void)n_in; (void)out_size;
  // 16384 elements / 32 per block (8 per wave x 4 waves)
  circuit_kernel<<<512, 256, 0, stream>>>(x, params, out);
}